// Round 3
// baseline (60.020 us; speedup 1.0000x reference)
//
#include <hip/hip_runtime.h>

// Problem constants (match reference)
#define BDIM 4096
#define LDIM 128
#define FDIM 64
#define NVALS 129      // counts range 0..128
#define NODE_MAX 1024  // id domain [0, 1024)

typedef float f32x4 __attribute__((ext_vector_type(4)));   // native vector: nontemporal-store OK

// ---------------------------------------------------------------------------
// Kernel 1: build lookup table T[v][g] = sum_f relu(v*W1[f]+b1[f]) * W2[f][g] + b2[g]
// feat(pos) = T[self_cnt] + T[cross_cnt]  (masked pos -> T[0]+T[0], which equals
// the reference's encode of freq=(0,0): 2*(relu(b1)@W2 + b2)).
// grid = 129 blocks, block = 64 threads (one wave).
// ---------------------------------------------------------------------------
__global__ __launch_bounds__(FDIM) void build_table_kernel(
    const float* __restrict__ W1, const float* __restrict__ b1,
    const float* __restrict__ W2, const float* __restrict__ b2,
    float* __restrict__ T)
{
    const int v = blockIdx.x;    // count value 0..128
    const int g = threadIdx.x;   // output feature 0..63

    __shared__ float h[FDIM];
    h[g] = fmaxf((float)v * W1[g] + b1[g], 0.0f);   // relu(v*W1[f]+b1[f])
    __syncthreads();

    float acc = b2[g];
#pragma unroll
    for (int f = 0; f < FDIM; ++f)
        acc = fmaf(h[f], W2[f * FDIM + g], acc);    // W2 is [F,F] row-major: W2[f][g]

    T[v * FDIM + g] = acc;
}

// ---------------------------------------------------------------------------
// Kernel 2: one block per batch row. 256 threads.
//   Phase A: zero two 1024-entry LDS histograms; stage src/dst ids in LDS.
//   Phase B: 128+128 LDS atomicAdds build per-row id histograms; counts are
//            then two LDS reads per position (replaces the O(L^2) scan —
//            ~1K LDS ops/block instead of ~65K).
//   Phase C: all 256 threads stream the 2x128x64 f32 outputs as nontemporal
//            float4, gathering T[a]+T[b] (table is L1/L2-hot, 33 KB).
// ---------------------------------------------------------------------------
__global__ __launch_bounds__(256) void encode_rows_kernel(
    const int* __restrict__ src, const int* __restrict__ dst,
    const float* __restrict__ T,
    float* __restrict__ out_src, float* __restrict__ out_dst)
{
    const int b = blockIdx.x;
    const int t = threadIdx.x;

    __shared__ int sID[LDIM], dID[LDIM];
    __shared__ int histS[NODE_MAX], histD[NODE_MAX];
    __shared__ int aS[LDIM], bS[LDIM], aD[LDIM], bD[LDIM];

    // Phase A: zero histograms (one int4 per thread per array) + load ids.
    ((int4*)histS)[t] = make_int4(0, 0, 0, 0);
    ((int4*)histD)[t] = make_int4(0, 0, 0, 0);
    if (t < LDIM) sID[t] = src[(size_t)b * LDIM + t];
    else          dID[t - LDIM] = dst[(size_t)b * LDIM + (t - LDIM)];
    __syncthreads();

    // Phase B1: histogram build (order-independent -> deterministic).
    if (t < LDIM) atomicAdd(&histS[sID[t]], 1);
    else          atomicAdd(&histD[dID[t - LDIM]], 1);
    __syncthreads();

    // Phase B2: per-position counts via two LDS reads.
    if (t < LDIM) {
        const int id = sID[t];
        int a = histS[id], c = histD[id];
        if (id == 0) { a = 0; c = 0; }   // padding mask -> freq (0,0)
        aS[t] = a; bS[t] = c;
    } else {
        const int id = dID[t - LDIM];
        int a = histD[id], c = histS[id];
        if (id == 0) { a = 0; c = 0; }
        aD[t - LDIM] = a; bD[t - LDIM] = c;
    }
    __syncthreads();

    // Phase C: write 128 positions x 64 floats = 2048 float4 per side.
    const f32x4* __restrict__ T4 = (const f32x4*)T;        // T4[v*16 + chunk]
    f32x4* __restrict__ o4s = (f32x4*)out_src;
    f32x4* __restrict__ o4d = (f32x4*)out_dst;
    const size_t rowBase = (size_t)b * (LDIM * FDIM / 4);  // 2048 float4 per row

#pragma unroll
    for (int k = 0; k < 8; ++k) {
        const int c   = t + k * 256;     // 0..2047
        const int pos = c >> 4;          // position within row
        const int ch  = c & 15;          // float4 chunk within the 64-float feature

        {
            const f32x4 r = T4[aS[pos] * 16 + ch] + T4[bS[pos] * 16 + ch];
            __builtin_nontemporal_store(r, &o4s[rowBase + c]);
        }
        {
            const f32x4 r = T4[aD[pos] * 16 + ch] + T4[bD[pos] * 16 + ch];
            __builtin_nontemporal_store(r, &o4d[rowBase + c]);
        }
    }
}

extern "C" void kernel_launch(void* const* d_in, const int* in_sizes, int n_in,
                              void* d_out, int out_size, void* d_ws, size_t ws_size,
                              hipStream_t stream)
{
    const int*   src = (const int*)d_in[0];    // int64 in ref -> int32 from harness
    const int*   dst = (const int*)d_in[1];
    const float* W1  = (const float*)d_in[2];  // [1,F]
    const float* b1  = (const float*)d_in[3];  // [F]
    const float* W2  = (const float*)d_in[4];  // [F,F]
    const float* b2  = (const float*)d_in[5];  // [F]

    float* out = (float*)d_out;                // [src_feat | dst_feat], each B*L*F f32
    float* T   = (float*)d_ws;                 // 129*64 f32 = 33 KB lookup table

    const int B = in_sizes[0] / LDIM;          // 4096
    const size_t half = (size_t)B * LDIM * FDIM;

    build_table_kernel<<<NVALS, FDIM, 0, stream>>>(W1, b1, W2, b2, T);
    encode_rows_kernel<<<B, 256, 0, stream>>>(src, dst, T, out, out + half);
}

// Round 4
// 53.370 us; speedup vs baseline: 1.1246x; 1.1246x over previous
//
#include <hip/hip_runtime.h>

// Problem constants (match reference)
#define LDIM 128
#define FDIM 64
#define NVALS 129      // counts range 0..128
#define NODE_MAX 1024  // id domain [0, 1024)

typedef float f32x4 __attribute__((ext_vector_type(4)));

// ---------------------------------------------------------------------------
// Kernel A (prep): grid = 33 + B blocks, 256 threads.
//   blocks [0,33):   lookup table T[v][g] = relu(v*W1+b1)@W2 + b2, 4 v's/block
//   blocks [33,33+B): per-row counts via LDS histogram, packed as u16
//                     (self | cross<<8), one per position, src rows then dst.
// feat(pos) = T[self] + T[cross]; masked pos -> T[0]+T[0] == encode of (0,0).
// ---------------------------------------------------------------------------
__global__ __launch_bounds__(256) void prep_kernel(
    const int* __restrict__ src, const int* __restrict__ dst,
    const float* __restrict__ W1, const float* __restrict__ b1,
    const float* __restrict__ W2, const float* __restrict__ b2,
    float* __restrict__ T, unsigned short* __restrict__ idx, int B)
{
    const int t = threadIdx.x;

    if (blockIdx.x < 33) {
        // ---- table part: v = 4*blk + (t>>6), g = t&63 ----
        const int vi = t >> 6, g = t & 63;
        const int v  = blockIdx.x * 4 + vi;
        __shared__ float h[4][FDIM];
        h[vi][g] = fmaxf((float)v * W1[g] + b1[g], 0.0f);
        __syncthreads();
        if (v < NVALS) {
            float acc = b2[g];
#pragma unroll
            for (int f = 0; f < FDIM; ++f)
                acc = fmaf(h[vi][f], W2[f * FDIM + g], acc);  // W2[f][g]
            T[v * FDIM + g] = acc;
        }
        return;
    }

    // ---- counts part ----
    const int row = blockIdx.x - 33;
    __shared__ int sID[LDIM], dID[LDIM];
    __shared__ int histS[NODE_MAX], histD[NODE_MAX];

    ((int4*)histS)[t] = make_int4(0, 0, 0, 0);
    ((int4*)histD)[t] = make_int4(0, 0, 0, 0);
    if (t < LDIM) sID[t] = src[(size_t)row * LDIM + t];
    else          dID[t - LDIM] = dst[(size_t)row * LDIM + (t - LDIM)];
    __syncthreads();

    if (t < LDIM) atomicAdd(&histS[sID[t]], 1);
    else          atomicAdd(&histD[dID[t - LDIM]], 1);
    __syncthreads();

    if (t < LDIM) {
        const int id = sID[t];
        int a = histS[id], c = histD[id];        // [self in src, cross in dst]
        if (id == 0) { a = 0; c = 0; }
        idx[(size_t)row * LDIM + t] = (unsigned short)(a | (c << 8));
    } else {
        const int p = t - LDIM;
        const int id = dID[p];
        int a = histD[id], c = histS[id];        // [self in dst, cross in src]
        if (id == 0) { a = 0; c = 0; }
        idx[(size_t)(B + row) * LDIM + p] = (unsigned short)(a | (c << 8));
    }
}

// ---------------------------------------------------------------------------
// Kernel B (stream): pure gather+store. No LDS, no barriers, no prologue.
// One f32x4 of output per loop step; e = c>>4 selects the position's packed
// counts (16 lanes broadcast-share it); two 256B-coalesced table gathers.
// ---------------------------------------------------------------------------
__global__ __launch_bounds__(256) void stream_kernel(
    const unsigned short* __restrict__ idx, const float* __restrict__ T,
    f32x4* __restrict__ out, int total4)
{
    const f32x4* __restrict__ T4 = (const f32x4*)T;   // T4[v*16 + ch]
    const int tid    = blockIdx.x * 256 + threadIdx.x;
    const int stride = gridDim.x * 256;
#pragma unroll 8
    for (int c = tid; c < total4; c += stride) {
        const int e  = c >> 4;          // position index in [2*B*L)
        const int ch = c & 15;          // float4 chunk within 64-float feature
        const unsigned int p = idx[e];
        out[c] = T4[(p & 255u) * 16 + ch] + T4[(p >> 8) * 16 + ch];
    }
}

// ---------------------------------------------------------------------------
// Fallback (ws too small for the 2MB index): R1-style fused kernel.
// ---------------------------------------------------------------------------
__global__ __launch_bounds__(256) void encode_rows_kernel(
    const int* __restrict__ src, const int* __restrict__ dst,
    const float* __restrict__ T,
    float* __restrict__ out_src, float* __restrict__ out_dst)
{
    const int b = blockIdx.x;
    const int t = threadIdx.x;

    __shared__ int sID[LDIM], dID[LDIM];
    __shared__ int histS[NODE_MAX], histD[NODE_MAX];
    __shared__ int aS[LDIM], bS[LDIM], aD[LDIM], bD[LDIM];

    ((int4*)histS)[t] = make_int4(0, 0, 0, 0);
    ((int4*)histD)[t] = make_int4(0, 0, 0, 0);
    if (t < LDIM) sID[t] = src[(size_t)b * LDIM + t];
    else          dID[t - LDIM] = dst[(size_t)b * LDIM + (t - LDIM)];
    __syncthreads();

    if (t < LDIM) atomicAdd(&histS[sID[t]], 1);
    else          atomicAdd(&histD[dID[t - LDIM]], 1);
    __syncthreads();

    if (t < LDIM) {
        const int id = sID[t];
        int a = histS[id], c = histD[id];
        if (id == 0) { a = 0; c = 0; }
        aS[t] = a; bS[t] = c;
    } else {
        const int id = dID[t - LDIM];
        int a = histD[id], c = histS[id];
        if (id == 0) { a = 0; c = 0; }
        aD[t - LDIM] = a; bD[t - LDIM] = c;
    }
    __syncthreads();

    const f32x4* __restrict__ T4 = (const f32x4*)T;
    f32x4* __restrict__ o4s = (f32x4*)out_src;
    f32x4* __restrict__ o4d = (f32x4*)out_dst;
    const size_t rowBase = (size_t)b * (LDIM * FDIM / 4);

#pragma unroll
    for (int k = 0; k < 8; ++k) {
        const int c   = t + k * 256;
        const int pos = c >> 4;
        const int ch  = c & 15;
        o4s[rowBase + c] = T4[aS[pos] * 16 + ch] + T4[bS[pos] * 16 + ch];
        o4d[rowBase + c] = T4[aD[pos] * 16 + ch] + T4[bD[pos] * 16 + ch];
    }
}

extern "C" void kernel_launch(void* const* d_in, const int* in_sizes, int n_in,
                              void* d_out, int out_size, void* d_ws, size_t ws_size,
                              hipStream_t stream)
{
    const int*   src = (const int*)d_in[0];
    const int*   dst = (const int*)d_in[1];
    const float* W1  = (const float*)d_in[2];  // [1,F]
    const float* b1  = (const float*)d_in[3];  // [F]
    const float* W2  = (const float*)d_in[4];  // [F,F]
    const float* b2  = (const float*)d_in[5];  // [F]

    float* out = (float*)d_out;                // [src_feat | dst_feat]
    float* T   = (float*)d_ws;                 // 129*64 f32 = 33 KB

    const int B = in_sizes[0] / LDIM;          // 4096
    const size_t idx_off   = 33280;            // 33 KB table, 256B-aligned slot after
    const size_t idx_bytes = (size_t)2 * B * LDIM * sizeof(unsigned short);

    if (ws_size >= idx_off + idx_bytes) {
        unsigned short* idx = (unsigned short*)((char*)d_ws + idx_off);
        const int total4 = 2 * B * LDIM * (FDIM / 4);          // 16,777,216
        const int nblk   = (total4 / (256 * 8)) > 0 ? (total4 / (256 * 8)) : 1;
        prep_kernel<<<33 + B, 256, 0, stream>>>(src, dst, W1, b1, W2, b2, T, idx, B);
        stream_kernel<<<nblk, 256, 0, stream>>>(idx, T, (f32x4*)out, total4);
    } else {
        // Fallback: fused path (table blocks first would race; reuse prep for
        // table only via its first 33 blocks by passing idx==nullptr is unsafe,
        // so build table with prep's table part folded into encode's grid is
        // overkill — just run prep's table blocks alone, then fused encode).
        prep_kernel<<<33, 256, 0, stream>>>(src, dst, W1, b1, W2, b2, T,
                                            (unsigned short*)nullptr, B);
        const size_t half = (size_t)B * LDIM * FDIM;
        encode_rows_kernel<<<B, 256, 0, stream>>>(src, dst, T, out, out + half);
    }
}